// Round 12
// baseline (470.439 us; speedup 1.0000x reference)
//
#include <hip/hip_runtime.h>
#include <float.h>

// Pipeline (replica-f32 semantics confirmed passing in rounds 5-11):
//   conv1/2/3: f32 sequential fused-FMA (ic,kh,kw), bias at end, relu  [exact]
//              conv2/3: row-coalesced float2 loads + neighbor shuffles for
//              taps (identical tap values; chain order unchanged).
//   rownorm:   sx/sc pairwise-8                                        [exact]
//   split:     x,c -> bf16 hi/lo pairs; zero count + out[16384]
//   screen:    MFMA bf16x3, A-in-registers (16-row blocks, 8 waves/SIMD),
//              all 8192 codes; top-2 of g = fmaf(-2,acc,sc); writes out[]
//              when gap >= TAU, else appends row to list, qbest[row]=~0
//   fix:       coalesced LDS-tiled exact replica recompute of flagged rows;
//              winner via atomicMin on key=(q_bits<<32)|k (q>0)
//   vq_out:    writes out[row] for flagged rows from qbest
//
// Workspace (float slots, ~54.9 MB). Split arrays alias out1:
//   out1 : ws[0 .. 8388608)
//     xh = ws+0        (ushort[1048576])
//     xl = ws+524288   (ushort[1048576])
//     ch = ws+1048576  (ushort[524288])
//     cl = ws+1310720  (ushort[524288])
//   out2 : ws+8388608   [16][64][64][64]
//   flat : ws+12582912  [16384][64]
//   sx   : ws+13631488  [16384]
//   sc   : ws+13647872  [8192]
//   count: ws+13656064  (int)
//   list : ws+13656320  (int[16384])
//   qbest: ws+13672704  (u64[16384], 8B aligned)

#define TAU 4e-6f

typedef __attribute__((ext_vector_type(8))) short s16x8;
typedef __attribute__((ext_vector_type(4))) float f32x4;
typedef unsigned short ushort_t;
typedef unsigned long long u64;

static __device__ __forceinline__ unsigned short f2bf(float f) {
    unsigned u = __float_as_uint(f);
    u = (u + 0x7fffu + ((u >> 16) & 1u)) >> 16;    // RN-even; no NaN in this data
    return (unsigned short)u;
}
static __device__ __forceinline__ float bf2f(unsigned short h) {
    return __uint_as_float(((unsigned)h) << 16);
}

// ---------------- conv1: x[16,3,256,256] -> relu -> out1[16,32,128,128], k4 s2 p1
__global__ __launch_bounds__(256) void conv1_kernel(const float* __restrict__ in,
                                                    const float* __restrict__ w,   // [32][3][4][4]
                                                    const float* __restrict__ bias,// [32]
                                                    float* __restrict__ out) {
    int p = blockIdx.x * 256 + threadIdx.x;        // 262144
    int ow = p & 127, oh = (p >> 7) & 127, bb = p >> 14;
    int oc0 = blockIdx.y * 16;
    float taps[48];                                 // [ic][kh][kw]
    for (int ic = 0; ic < 3; ++ic) {
        const float* ip = in + (bb * 3 + ic) * 65536;
        #pragma unroll
        for (int kh = 0; kh < 4; ++kh) {
            int ih = oh * 2 - 1 + kh;
            #pragma unroll
            for (int kw = 0; kw < 4; ++kw) {
                int iw = ow * 2 - 1 + kw;
                bool ok = ((unsigned)ih < 256u) && ((unsigned)iw < 256u);
                taps[ic * 16 + kh * 4 + kw] = ok ? ip[ih * 256 + iw] : 0.0f;
            }
        }
    }
    float* op = out + bb * (32 * 16384) + oh * 128 + ow;
    for (int oc = oc0; oc < oc0 + 16; ++oc) {
        float acc = 0.0f;
        const float* wp = w + oc * 48;             // wave-uniform
        #pragma unroll
        for (int t = 0; t < 48; ++t) acc = __fmaf_rn(taps[t], wp[t], acc);
        acc = __fadd_rn(acc, bias[oc]);
        op[oc * 16384] = fmaxf(acc, 0.0f);
    }
}

// ---------------- conv2: out1 -> relu -> out2[16,64,64,64]
// wave = one 64-wide output row; taps via coalesced float2 + lane shuffles.
__global__ __launch_bounds__(256) void conv2_kernel(const float* __restrict__ in,
                                                    const float* __restrict__ w,   // [64][32][4][4]
                                                    const float* __restrict__ bias,
                                                    float* __restrict__ out) {
    int p = blockIdx.x * 256 + threadIdx.x;        // 65536 spatial
    int ow = p & 63, oh = (p >> 6) & 63, bb = p >> 12;   // ow == lane
    int oc0 = blockIdx.y * 8;
    float acc[8];
    #pragma unroll
    for (int j = 0; j < 8; ++j) acc[j] = 0.0f;
    const float* ibase = in + bb * 32 * 16384;

    for (int ic = 0; ic < 32; ++ic) {
        const float* ip = ibase + ic * 16384;
        float r0[4], r1[4];
        #pragma unroll
        for (int kh = 0; kh < 4; ++kh) {           // 4 independent coalesced loads
            int ih = oh * 2 - 1 + kh;              // wave-uniform branch
            float v0 = 0.0f, v1 = 0.0f;
            if ((unsigned)ih < 128u) {
                float2 t = *(const float2*)(ip + ih * 128 + 2 * ow);
                v0 = t.x; v1 = t.y;
            }
            r0[kh] = v0; r1[kh] = v1;
        }
        const float* wic = w + ic * 16;
        #pragma unroll
        for (int kh = 0; kh < 4; ++kh) {
            float t0 = __shfl_up(r1[kh], 1);
            if (ow == 0) t0 = 0.0f;                // iw = -1 pad
            float t3 = __shfl_down(r0[kh], 1);
            if (ow == 63) t3 = 0.0f;               // iw = 128 pad
            const float* wk = wic + kh * 4;        // wave-uniform
            #pragma unroll
            for (int j = 0; j < 8; ++j) acc[j] = __fmaf_rn(t0,     wk[(oc0 + j) * 512 + 0], acc[j]);
            #pragma unroll
            for (int j = 0; j < 8; ++j) acc[j] = __fmaf_rn(r0[kh], wk[(oc0 + j) * 512 + 1], acc[j]);
            #pragma unroll
            for (int j = 0; j < 8; ++j) acc[j] = __fmaf_rn(r1[kh], wk[(oc0 + j) * 512 + 2], acc[j]);
            #pragma unroll
            for (int j = 0; j < 8; ++j) acc[j] = __fmaf_rn(t3,     wk[(oc0 + j) * 512 + 3], acc[j]);
        }
    }
    float* op = out + bb * (64 * 4096) + oh * 64 + ow;
    #pragma unroll
    for (int j = 0; j < 8; ++j) {
        float y = __fadd_rn(acc[j], bias[oc0 + j]);
        op[(oc0 + j) * 4096] = fmaxf(y, 0.0f);
    }
}

// ---------------- conv3: out2 -> relu -> flat[16384][64]
// half-wave = one 32-wide output row; taps via coalesced float2 + shuffles.
__global__ __launch_bounds__(256) void conv3_kernel(const float* __restrict__ in,
                                                    const float* __restrict__ w,   // [64][64][4][4]
                                                    const float* __restrict__ bias,
                                                    float* __restrict__ flat) {
    int p = blockIdx.x * 256 + threadIdx.x;        // 16384 (== flat row)
    int ow = p & 31, oh = (p >> 5) & 31, bb = p >> 10;   // ow == lane&31
    int oc0 = blockIdx.y * 2;
    float acc[2];
    #pragma unroll
    for (int j = 0; j < 2; ++j) acc[j] = 0.0f;
    const float* ibase = in + bb * 64 * 4096;

    for (int ic = 0; ic < 64; ++ic) {
        const float* ip = ibase + ic * 4096;
        float r0[4], r1[4];
        #pragma unroll
        for (int kh = 0; kh < 4; ++kh) {
            int ih = oh * 2 - 1 + kh;              // per-lane (half-waves differ)
            float v0 = 0.0f, v1 = 0.0f;
            if ((unsigned)ih < 64u) {
                float2 t = *(const float2*)(ip + ih * 64 + 2 * ow);
                v0 = t.x; v1 = t.y;
            }
            r0[kh] = v0; r1[kh] = v1;
        }
        const float* wic = w + ic * 16;
        #pragma unroll
        for (int kh = 0; kh < 4; ++kh) {
            float t0 = __shfl_up(r1[kh], 1);
            if (ow == 0) t0 = 0.0f;                // also kills cross-half garbage
            float t3 = __shfl_down(r0[kh], 1);
            if (ow == 31) t3 = 0.0f;               // also kills cross-half garbage
            const float* wk = wic + kh * 4;
            #pragma unroll
            for (int j = 0; j < 2; ++j) acc[j] = __fmaf_rn(t0,     wk[(oc0 + j) * 1024 + 0], acc[j]);
            #pragma unroll
            for (int j = 0; j < 2; ++j) acc[j] = __fmaf_rn(r0[kh], wk[(oc0 + j) * 1024 + 1], acc[j]);
            #pragma unroll
            for (int j = 0; j < 2; ++j) acc[j] = __fmaf_rn(r1[kh], wk[(oc0 + j) * 1024 + 2], acc[j]);
            #pragma unroll
            for (int j = 0; j < 2; ++j) acc[j] = __fmaf_rn(t3,     wk[(oc0 + j) * 1024 + 3], acc[j]);
        }
    }
    float* op = flat + (size_t)p * 64 + oc0;
    #pragma unroll
    for (int j = 0; j < 2; ++j) {
        float y = __fadd_rn(acc[j], bias[oc0 + j]);
        op[j] = fmaxf(y, 0.0f);
    }
}

// ---------------- row norms: sx[16384], sc[8192] (pairwise-8)
__global__ __launch_bounds__(256) void rownorm_kernel(const float* __restrict__ flat,
                                                      const float* __restrict__ cb,
                                                      float* __restrict__ sx,
                                                      float* __restrict__ sc) {
    int i = blockIdx.x * 256 + threadIdx.x;        // 24576
    const float* src;
    float* dst;
    if (i < 16384) { src = flat + (size_t)i * 64; dst = sx + i; }
    else           { src = cb + (size_t)(i - 16384) * 64; dst = sc + (i - 16384); }
    float r[8];
    #pragma unroll
    for (int j = 0; j < 8; ++j) r[j] = __fmul_rn(src[j], src[j]);
    #pragma unroll
    for (int b = 1; b < 8; ++b)
        #pragma unroll
        for (int j = 0; j < 8; ++j)
            r[j] = __fadd_rn(r[j], __fmul_rn(src[b * 8 + j], src[b * 8 + j]));
    float s01 = __fadd_rn(r[0], r[1]), s23 = __fadd_rn(r[2], r[3]);
    float s45 = __fadd_rn(r[4], r[5]), s67 = __fadd_rn(r[6], r[7]);
    *dst = __fadd_rn(__fadd_rn(s01, s23), __fadd_rn(s45, s67));
}

// ---------------- split: f32 -> bf16 hi/lo; zero count + tuple scalar
__global__ __launch_bounds__(256) void split_kernel(const float* __restrict__ flat,
                                                    const float* __restrict__ cb,
                                                    ushort_t* __restrict__ xh,
                                                    ushort_t* __restrict__ xl,
                                                    ushort_t* __restrict__ ch,
                                                    ushort_t* __restrict__ cl,
                                                    int* __restrict__ count,
                                                    float* __restrict__ out) {
    int i = blockIdx.x * 256 + threadIdx.x;        // 1572864
    if (i == 0) { *count = 0; out[16384] = 0.0f; }
    float v;
    ushort_t *ph, *pl;
    if (i < 1048576) { v = flat[i]; ph = xh + i; pl = xl + i; }
    else             { int j = i - 1048576; v = cb[j]; ph = ch + j; pl = cl + j; }
    unsigned short h = f2bf(v);
    unsigned short l = f2bf(v - bf2f(h));
    *ph = h; *pl = l;
}

// ---------------- MFMA screen: 1024 blocks x 16 rows; all 8192 codes.
// 512 threads = 8 waves; wave w owns cols nb*128 + w*16 + le per nb step.
__global__ __launch_bounds__(512) void vq_screen_kernel(const ushort_t* __restrict__ xh,
                                                        const ushort_t* __restrict__ xl,
                                                        const ushort_t* __restrict__ ch,
                                                        const ushort_t* __restrict__ cl,
                                                        const float* __restrict__ sc,
                                                        float* __restrict__ out,
                                                        int* __restrict__ count,
                                                        int* __restrict__ list,
                                                        u64* __restrict__ qbest) {
    __shared__ float lm1[8][16];
    __shared__ int   li1[8][16];
    __shared__ float lm2[8][16];
    int tid = threadIdx.x;
    int row0 = blockIdx.x * 16;
    int w = tid >> 6, lane = tid & 63;
    int le = lane & 15, lk = lane >> 4;

    // A fragments in registers (rows row0+le), reused across all codes
    s16x8 a0, a1, a2, a3;
    {
        size_t ar = (size_t)(row0 + le) * 64 + lk * 8;
        a0 = *(const s16x8*)(xh + ar);
        a1 = *(const s16x8*)(xh + ar + 32);
        a2 = *(const s16x8*)(xl + ar);
        a3 = *(const s16x8*)(xl + ar + 32);
    }

    float m1[4], m2[4];
    int i1[4];
    #pragma unroll
    for (int s = 0; s < 4; ++s) { m1[s] = FLT_MAX; m2[s] = FLT_MAX; i1[s] = 0x7fffffff; }

    int colbase = w * 16 + le;
    for (int nb = 0; nb < 64; ++nb) {
        int col = nb * 128 + colbase;              // this lane's code (B-row)
        size_t br = (size_t)col * 64 + lk * 8;
        s16x8 bh0 = *(const s16x8*)(ch + br);
        s16x8 bh1 = *(const s16x8*)(ch + br + 32);
        s16x8 bl0 = *(const s16x8*)(cl + br);
        s16x8 bl1 = *(const s16x8*)(cl + br + 32);
        float scv = sc[col];

        f32x4 acc = (f32x4){0.f, 0.f, 0.f, 0.f};
        acc = __builtin_amdgcn_mfma_f32_16x16x32_bf16(a0, bh0, acc, 0, 0, 0);
        acc = __builtin_amdgcn_mfma_f32_16x16x32_bf16(a1, bh1, acc, 0, 0, 0);
        acc = __builtin_amdgcn_mfma_f32_16x16x32_bf16(a0, bl0, acc, 0, 0, 0);
        acc = __builtin_amdgcn_mfma_f32_16x16x32_bf16(a1, bl1, acc, 0, 0, 0);
        acc = __builtin_amdgcn_mfma_f32_16x16x32_bf16(a2, bh0, acc, 0, 0, 0);
        acc = __builtin_amdgcn_mfma_f32_16x16x32_bf16(a3, bh1, acc, 0, 0, 0);

        // epilogue: g = fl(-2*dot + sc), running top-2 (ascending col order)
        #pragma unroll
        for (int reg = 0; reg < 4; ++reg) {
            float g = __fmaf_rn(-2.0f, acc[reg], scv);   // proxy (sx dropped)
            float om1 = m1[reg];
            m2[reg] = __builtin_amdgcn_fmed3f(om1, m2[reg], g);
            i1[reg] = (g < om1) ? col : i1[reg];
            m1[reg] = fminf(om1, g);
        }
    }

    // merge across the 16 le-lanes (D col = le; D row = lk*4+reg)
    #pragma unroll
    for (int reg = 0; reg < 4; ++reg) {
        float v1 = m1[reg], v2 = m2[reg];
        int ix = i1[reg];
        #pragma unroll
        for (int mask = 1; mask < 16; mask <<= 1) {
            float o1 = __shfl_xor(v1, mask);
            int oi = __shfl_xor(ix, mask);
            float o2 = __shfl_xor(v2, mask);
            float n2 = fminf(fminf(v2, o2), fmaxf(v1, o1));
            ix = (o1 < v1) ? oi : ((o1 == v1 && oi < ix) ? oi : ix);
            v1 = fminf(v1, o1);
            v2 = n2;
        }
        if (le == 0) {
            int rl = lk * 4 + reg;
            lm1[w][rl] = v1; li1[w][rl] = ix; lm2[w][rl] = v2;
        }
    }
    __syncthreads();
    if (tid < 16) {
        float M1 = FLT_MAX, M2 = FLT_MAX;
        int I1 = 0x7fffffff;
        #pragma unroll
        for (int ww = 0; ww < 8; ++ww) {
            float a1v = lm1[ww][tid], a2v = lm2[ww][tid];
            int ai = li1[ww][tid];
            M2 = fminf(fminf(M2, a2v), fmaxf(M1, a1v));
            if (a1v < M1 || (a1v == M1 && ai < I1)) I1 = ai;
            M1 = fminf(M1, a1v);
        }
        int row = row0 + tid;
        if (M2 - M1 >= TAU) {
            out[row] = (float)I1;                  // provably the replica argmin
        } else {
            qbest[row] = 0xFFFFFFFFFFFFFFFFull;
            int pos = atomicAdd(count, 1);
            list[pos] = row;
        }
    }
}

// ---------------- fix: coalesced exact replica recompute of flagged rows.
// grid (256 rowchunks, 64 codetiles); block = 64 rows x 128 codes.
#define FLDP 68
__global__ __launch_bounds__(256) void vq_fix_kernel(const float* __restrict__ flat,
                                                     const float* __restrict__ cb,
                                                     const float* __restrict__ sx,
                                                     const float* __restrict__ sc,
                                                     const int* __restrict__ count,
                                                     const int* __restrict__ list,
                                                     u64* __restrict__ qbest) {
    __shared__ float xs[64 * FLDP];
    __shared__ float cs[128 * FLDP];
    __shared__ float sxs[64], scs[128];
    __shared__ int rowids[64];
    int n = *count;
    int rb = blockIdx.x;
    if (rb * 64 >= n) return;
    int nrows = n - rb * 64; if (nrows > 64) nrows = 64;
    int cb0 = blockIdx.y * 128;
    int tid = threadIdx.x;

    // stage rows (gather) + sx + rowids
    #pragma unroll
    for (int s = 0; s < 4; ++s) {
        int idx = tid + 256 * s;                   // 1024 float4s
        int r = idx >> 4, c = idx & 15;
        int rr = rb * 64 + r; if (rr >= n) rr = n - 1;
        int row = list[rr];
        if (c == 0) { rowids[r] = row; sxs[r] = sx[row]; }
        *(float4*)&xs[r * FLDP + c * 4] = *(const float4*)(flat + (size_t)row * 64 + c * 4);
    }
    // stage codes (coalesced)
    #pragma unroll
    for (int s = 0; s < 8; ++s) {
        int idx = tid + 256 * s;                   // 2048 float4s
        int r = idx >> 4, c = idx & 15;
        *(float4*)&cs[r * FLDP + c * 4] = *(const float4*)(cb + (size_t)(cb0 + r) * 64 + c * 4);
    }
    if (tid < 128) scs[tid] = sc[cb0 + tid];
    __syncthreads();

    int tr = tid >> 4, tc = tid & 15;              // rows tr+16i (i<4), codes tc+16j (j<8)
    float acc[4][8];
    #pragma unroll
    for (int i = 0; i < 4; ++i)
        #pragma unroll
        for (int j = 0; j < 8; ++j) acc[i][j] = 0.0f;

    for (int d = 0; d < 64; d += 4) {              // strictly ascending d: replica chain
        float4 ax[4], bc[8];
        #pragma unroll
        for (int i = 0; i < 4; ++i) ax[i] = *(const float4*)&xs[(tr + 16 * i) * FLDP + d];
        #pragma unroll
        for (int j = 0; j < 8; ++j) bc[j] = *(const float4*)&cs[(tc + 16 * j) * FLDP + d];
        #pragma unroll
        for (int i = 0; i < 4; ++i)
            #pragma unroll
            for (int j = 0; j < 8; ++j) {
                acc[i][j] = __fmaf_rn(ax[i].x, bc[j].x, acc[i][j]);
                acc[i][j] = __fmaf_rn(ax[i].y, bc[j].y, acc[i][j]);
                acc[i][j] = __fmaf_rn(ax[i].z, bc[j].z, acc[i][j]);
                acc[i][j] = __fmaf_rn(ax[i].w, bc[j].w, acc[i][j]);
            }
    }

    float best[4];
    int bidx[4];
    #pragma unroll
    for (int i = 0; i < 4; ++i) { best[i] = FLT_MAX; bidx[i] = 0x7fffffff; }
    #pragma unroll
    for (int j = 0; j < 8; ++j) {                  // ascending k within lane
        int k = cb0 + tc + 16 * j;
        float scj = scs[tc + 16 * j];
        #pragma unroll
        for (int i = 0; i < 4; ++i) {
            float t1 = __fadd_rn(sxs[tr + 16 * i], scj);
            float q = __fmaf_rn(-2.0f, acc[i][j], t1);   // replica q
            if (q < best[i]) { best[i] = q; bidx[i] = k; }
        }
    }

    // per-row merge across tc (reuse cs)
    __syncthreads();
    float* rmin = cs;                              // [64][16]
    int* ridx = (int*)(cs + 1024);                 // [64][16]
    #pragma unroll
    for (int i = 0; i < 4; ++i) {
        rmin[(tr + 16 * i) * 16 + tc] = best[i];
        ridx[(tr + 16 * i) * 16 + tc] = bidx[i];
    }
    __syncthreads();
    if (tid < nrows) {
        float m = FLT_MAX; int mi = 0x7fffffff;
        for (int t2 = 0; t2 < 16; ++t2) {
            float v = rmin[tid * 16 + t2];
            int ix = ridx[tid * 16 + t2];
            if (v < m || (v == m && ix < mi)) { m = v; mi = ix; }
        }
        u64 key = ((u64)__float_as_uint(m) << 32) | (unsigned)mi;  // q>0 -> order ok
        atomicMin(&qbest[rowids[tid]], key);
    }
}

// ---------------- vq_out: write flagged rows from qbest
__global__ __launch_bounds__(256) void vq_out_kernel(const int* __restrict__ count,
                                                     const int* __restrict__ list,
                                                     const u64* __restrict__ qbest,
                                                     float* __restrict__ out) {
    int pos = blockIdx.x * 256 + threadIdx.x;      // 16384
    if (pos >= *count) return;
    int row = list[pos];
    out[row] = (float)(unsigned)(qbest[row] & 0xffffffffull);
}

extern "C" void kernel_launch(void* const* d_in, const int* in_sizes, int n_in,
                              void* d_out, int out_size, void* d_ws, size_t ws_size,
                              hipStream_t stream) {
    const float* x  = (const float*)d_in[0];
    const float* w1 = (const float*)d_in[1];
    const float* b1 = (const float*)d_in[2];
    const float* w2 = (const float*)d_in[3];
    const float* b2 = (const float*)d_in[4];
    const float* w3 = (const float*)d_in[5];
    const float* b3 = (const float*)d_in[6];
    const float* cb = (const float*)d_in[7];

    float* ws   = (float*)d_ws;
    float* out1 = ws;                               // [0, 8388608)
    ushort_t* xh = (ushort_t*)(ws + 0);             // aliases out1 (post-conv2)
    ushort_t* xl = (ushort_t*)(ws + 524288);
    ushort_t* ch = (ushort_t*)(ws + 1048576);
    ushort_t* cl = (ushort_t*)(ws + 1310720);
    float* out2 = ws + 8388608;
    float* flat = ws + 12582912;
    float* sx   = ws + 13631488;
    float* sc   = ws + 13647872;
    int*   count = (int*)(ws + 13656064);
    int*   list  = (int*)(ws + 13656320);
    u64*   qbest = (u64*)(ws + 13672704);           // 8B aligned
    float* out  = (float*)d_out;

    hipLaunchKernelGGL(conv1_kernel,  dim3(1024, 2), dim3(256), 0, stream, x, w1, b1, out1);
    hipLaunchKernelGGL(conv2_kernel,  dim3(256, 8), dim3(256), 0, stream, out1, w2, b2, out2);
    hipLaunchKernelGGL(conv3_kernel,  dim3(64, 32), dim3(256), 0, stream, out2, w3, b3, flat);
    hipLaunchKernelGGL(rownorm_kernel, dim3(96), dim3(256), 0, stream, flat, cb, sx, sc);
    hipLaunchKernelGGL(split_kernel,  dim3(6144), dim3(256), 0, stream, flat, cb, xh, xl, ch, cl, count, out);
    hipLaunchKernelGGL(vq_screen_kernel, dim3(1024), dim3(512), 0, stream,
                       xh, xl, ch, cl, sc, out, count, list, qbest);
    hipLaunchKernelGGL(vq_fix_kernel, dim3(256, 64), dim3(256), 0, stream,
                       flat, cb, sx, sc, count, list, qbest);
    hipLaunchKernelGGL(vq_out_kernel, dim3(64), dim3(256), 0, stream, count, list, qbest, out);
}

// Round 13
// 303.264 us; speedup vs baseline: 1.5513x; 1.5513x over previous
//
#include <hip/hip_runtime.h>
#include <float.h>

// Pipeline (replica-f32 semantics confirmed passing in rounds 5-12):
//   conv1/2/3: f32 sequential fused-FMA (ic,kh,kw), bias at end, relu  [exact]
//              conv2/3: row-coalesced float2 loads + neighbor shuffles for
//              taps + ic+1 prefetch (identical tap values; chain unchanged).
//   rownorm:   sx/sc pairwise-8                                        [exact]
//   split:     x,c -> bf16 hi/lo pairs; zero count + out[16384]
//   screen:    MFMA bf16x3, A-in-registers (64-row blocks, 4x A-reuse),
//              all 8192 codes; top-2 of g = fmaf(-2,acc,sc); writes out[]
//              when gap >= TAU, else appends row to list, qbest[row]=~0
//   fix:       coalesced LDS-tiled exact replica recompute of flagged rows;
//              winner via atomicMin on key=(q_bits<<32)|k (q>0)
//   vq_out:    writes out[row] for flagged rows from qbest
//
// Workspace (float slots, ~54.9 MB). Split arrays alias out1:
//   out1 : ws[0 .. 8388608)
//     xh = ws+0        (ushort[1048576])
//     xl = ws+524288   (ushort[1048576])
//     ch = ws+1048576  (ushort[524288])
//     cl = ws+1310720  (ushort[524288])
//   out2 : ws+8388608   [16][64][64][64]
//   flat : ws+12582912  [16384][64]
//   sx   : ws+13631488  [16384]
//   sc   : ws+13647872  [8192]
//   count: ws+13656064  (int)
//   list : ws+13656320  (int[16384])
//   qbest: ws+13672704  (u64[16384], 8B aligned)

#define TAU 4e-6f

typedef __attribute__((ext_vector_type(8))) short s16x8;
typedef __attribute__((ext_vector_type(4))) float f32x4;
typedef unsigned short ushort_t;
typedef unsigned long long u64;

static __device__ __forceinline__ unsigned short f2bf(float f) {
    unsigned u = __float_as_uint(f);
    u = (u + 0x7fffu + ((u >> 16) & 1u)) >> 16;    // RN-even; no NaN in this data
    return (unsigned short)u;
}
static __device__ __forceinline__ float bf2f(unsigned short h) {
    return __uint_as_float(((unsigned)h) << 16);
}

// ---------------- conv1: x[16,3,256,256] -> relu -> out1[16,32,128,128], k4 s2 p1
__global__ __launch_bounds__(256) void conv1_kernel(const float* __restrict__ in,
                                                    const float* __restrict__ w,   // [32][3][4][4]
                                                    const float* __restrict__ bias,// [32]
                                                    float* __restrict__ out) {
    int p = blockIdx.x * 256 + threadIdx.x;        // 262144
    int ow = p & 127, oh = (p >> 7) & 127, bb = p >> 14;
    int oc0 = blockIdx.y * 16;
    float taps[48];                                 // [ic][kh][kw]
    for (int ic = 0; ic < 3; ++ic) {
        const float* ip = in + (bb * 3 + ic) * 65536;
        #pragma unroll
        for (int kh = 0; kh < 4; ++kh) {
            int ih = oh * 2 - 1 + kh;
            #pragma unroll
            for (int kw = 0; kw < 4; ++kw) {
                int iw = ow * 2 - 1 + kw;
                bool ok = ((unsigned)ih < 256u) && ((unsigned)iw < 256u);
                taps[ic * 16 + kh * 4 + kw] = ok ? ip[ih * 256 + iw] : 0.0f;
            }
        }
    }
    float* op = out + bb * (32 * 16384) + oh * 128 + ow;
    for (int oc = oc0; oc < oc0 + 16; ++oc) {
        float acc = 0.0f;
        const float* wp = w + oc * 48;             // wave-uniform
        #pragma unroll
        for (int t = 0; t < 48; ++t) acc = __fmaf_rn(taps[t], wp[t], acc);
        acc = __fadd_rn(acc, bias[oc]);
        op[oc * 16384] = fmaxf(acc, 0.0f);
    }
}

// ---------------- conv2: out1 -> relu -> out2[16,64,64,64]
// wave = one 64-wide output row; coalesced float2 + shuffles; ic+1 prefetch.
__global__ __launch_bounds__(256) void conv2_kernel(const float* __restrict__ in,
                                                    const float* __restrict__ w,   // [64][32][4][4]
                                                    const float* __restrict__ bias,
                                                    float* __restrict__ out) {
    int p = blockIdx.x * 256 + threadIdx.x;        // 65536 spatial
    int ow = p & 63, oh = (p >> 6) & 63, bb = p >> 12;   // ow == lane
    int oc0 = blockIdx.y * 8;
    float acc[8];
    #pragma unroll
    for (int j = 0; j < 8; ++j) acc[j] = 0.0f;
    const float* ibase = in + bb * 32 * 16384;

    float r0[4], r1[4];
    #pragma unroll
    for (int kh = 0; kh < 4; ++kh) {               // initial load, ic = 0
        int ih = oh * 2 - 1 + kh;
        float v0 = 0.0f, v1 = 0.0f;
        if ((unsigned)ih < 128u) {
            float2 t = *(const float2*)(ibase + ih * 128 + 2 * ow);
            v0 = t.x; v1 = t.y;
        }
        r0[kh] = v0; r1[kh] = v1;
    }
    for (int ic = 0; ic < 32; ++ic) {
        float n0[4], n1[4];                         // prefetch ic+1 (clamped)
        int icn = (ic < 31) ? ic + 1 : 31;
        const float* ipn = ibase + icn * 16384;
        #pragma unroll
        for (int kh = 0; kh < 4; ++kh) {
            int ih = oh * 2 - 1 + kh;
            float v0 = 0.0f, v1 = 0.0f;
            if ((unsigned)ih < 128u) {
                float2 t = *(const float2*)(ipn + ih * 128 + 2 * ow);
                v0 = t.x; v1 = t.y;
            }
            n0[kh] = v0; n1[kh] = v1;
        }
        const float* wic = w + ic * 16;
        #pragma unroll
        for (int kh = 0; kh < 4; ++kh) {
            float t0 = __shfl_up(r1[kh], 1);
            if (ow == 0) t0 = 0.0f;                // iw = -1 pad
            float t3 = __shfl_down(r0[kh], 1);
            if (ow == 63) t3 = 0.0f;               // iw = 128 pad
            const float* wk = wic + kh * 4;        // wave-uniform
            #pragma unroll
            for (int j = 0; j < 8; ++j) acc[j] = __fmaf_rn(t0,     wk[(oc0 + j) * 512 + 0], acc[j]);
            #pragma unroll
            for (int j = 0; j < 8; ++j) acc[j] = __fmaf_rn(r0[kh], wk[(oc0 + j) * 512 + 1], acc[j]);
            #pragma unroll
            for (int j = 0; j < 8; ++j) acc[j] = __fmaf_rn(r1[kh], wk[(oc0 + j) * 512 + 2], acc[j]);
            #pragma unroll
            for (int j = 0; j < 8; ++j) acc[j] = __fmaf_rn(t3,     wk[(oc0 + j) * 512 + 3], acc[j]);
        }
        #pragma unroll
        for (int kh = 0; kh < 4; ++kh) { r0[kh] = n0[kh]; r1[kh] = n1[kh]; }
    }
    float* op = out + bb * (64 * 4096) + oh * 64 + ow;
    #pragma unroll
    for (int j = 0; j < 8; ++j) {
        float y = __fadd_rn(acc[j], bias[oc0 + j]);
        op[(oc0 + j) * 4096] = fmaxf(y, 0.0f);
    }
}

// ---------------- conv3: out2 -> relu -> flat[16384][64]
// half-wave = one 32-wide output row; coalesced float2 + shuffles; prefetch.
__global__ __launch_bounds__(256) void conv3_kernel(const float* __restrict__ in,
                                                    const float* __restrict__ w,   // [64][64][4][4]
                                                    const float* __restrict__ bias,
                                                    float* __restrict__ flat) {
    int p = blockIdx.x * 256 + threadIdx.x;        // 16384 (== flat row)
    int ow = p & 31, oh = (p >> 5) & 31, bb = p >> 10;   // ow == lane&31
    int oc0 = blockIdx.y * 4;
    float acc[4];
    #pragma unroll
    for (int j = 0; j < 4; ++j) acc[j] = 0.0f;
    const float* ibase = in + bb * 64 * 4096;

    float r0[4], r1[4];
    #pragma unroll
    for (int kh = 0; kh < 4; ++kh) {               // initial load, ic = 0
        int ih = oh * 2 - 1 + kh;
        float v0 = 0.0f, v1 = 0.0f;
        if ((unsigned)ih < 64u) {
            float2 t = *(const float2*)(ibase + ih * 64 + 2 * ow);
            v0 = t.x; v1 = t.y;
        }
        r0[kh] = v0; r1[kh] = v1;
    }
    for (int ic = 0; ic < 64; ++ic) {
        float n0[4], n1[4];                         // prefetch ic+1 (clamped)
        int icn = (ic < 63) ? ic + 1 : 63;
        const float* ipn = ibase + icn * 4096;
        #pragma unroll
        for (int kh = 0; kh < 4; ++kh) {
            int ih = oh * 2 - 1 + kh;
            float v0 = 0.0f, v1 = 0.0f;
            if ((unsigned)ih < 64u) {
                float2 t = *(const float2*)(ipn + ih * 64 + 2 * ow);
                v0 = t.x; v1 = t.y;
            }
            n0[kh] = v0; n1[kh] = v1;
        }
        const float* wic = w + ic * 16;
        #pragma unroll
        for (int kh = 0; kh < 4; ++kh) {
            float t0 = __shfl_up(r1[kh], 1);
            if (ow == 0) t0 = 0.0f;                // also kills cross-half garbage
            float t3 = __shfl_down(r0[kh], 1);
            if (ow == 31) t3 = 0.0f;               // also kills cross-half garbage
            const float* wk = wic + kh * 4;
            #pragma unroll
            for (int j = 0; j < 4; ++j) acc[j] = __fmaf_rn(t0,     wk[(oc0 + j) * 1024 + 0], acc[j]);
            #pragma unroll
            for (int j = 0; j < 4; ++j) acc[j] = __fmaf_rn(r0[kh], wk[(oc0 + j) * 1024 + 1], acc[j]);
            #pragma unroll
            for (int j = 0; j < 4; ++j) acc[j] = __fmaf_rn(r1[kh], wk[(oc0 + j) * 1024 + 2], acc[j]);
            #pragma unroll
            for (int j = 0; j < 4; ++j) acc[j] = __fmaf_rn(t3,     wk[(oc0 + j) * 1024 + 3], acc[j]);
        }
        #pragma unroll
        for (int kh = 0; kh < 4; ++kh) { r0[kh] = n0[kh]; r1[kh] = n1[kh]; }
    }
    float* op = flat + (size_t)p * 64 + oc0;
    #pragma unroll
    for (int j = 0; j < 4; ++j) {
        float y = __fadd_rn(acc[j], bias[oc0 + j]);
        op[j] = fmaxf(y, 0.0f);
    }
}

// ---------------- row norms: sx[16384], sc[8192] (pairwise-8)
__global__ __launch_bounds__(256) void rownorm_kernel(const float* __restrict__ flat,
                                                      const float* __restrict__ cb,
                                                      float* __restrict__ sx,
                                                      float* __restrict__ sc) {
    int i = blockIdx.x * 256 + threadIdx.x;        // 24576
    const float* src;
    float* dst;
    if (i < 16384) { src = flat + (size_t)i * 64; dst = sx + i; }
    else           { src = cb + (size_t)(i - 16384) * 64; dst = sc + (i - 16384); }
    float r[8];
    #pragma unroll
    for (int j = 0; j < 8; ++j) r[j] = __fmul_rn(src[j], src[j]);
    #pragma unroll
    for (int b = 1; b < 8; ++b)
        #pragma unroll
        for (int j = 0; j < 8; ++j)
            r[j] = __fadd_rn(r[j], __fmul_rn(src[b * 8 + j], src[b * 8 + j]));
    float s01 = __fadd_rn(r[0], r[1]), s23 = __fadd_rn(r[2], r[3]);
    float s45 = __fadd_rn(r[4], r[5]), s67 = __fadd_rn(r[6], r[7]);
    *dst = __fadd_rn(__fadd_rn(s01, s23), __fadd_rn(s45, s67));
}

// ---------------- split: f32 -> bf16 hi/lo; zero count + tuple scalar
__global__ __launch_bounds__(256) void split_kernel(const float* __restrict__ flat,
                                                    const float* __restrict__ cb,
                                                    ushort_t* __restrict__ xh,
                                                    ushort_t* __restrict__ xl,
                                                    ushort_t* __restrict__ ch,
                                                    ushort_t* __restrict__ cl,
                                                    int* __restrict__ count,
                                                    float* __restrict__ out) {
    int i = blockIdx.x * 256 + threadIdx.x;        // 1572864
    if (i == 0) { *count = 0; out[16384] = 0.0f; }
    float v;
    ushort_t *ph, *pl;
    if (i < 1048576) { v = flat[i]; ph = xh + i; pl = xl + i; }
    else             { int j = i - 1048576; v = cb[j]; ph = ch + j; pl = cl + j; }
    unsigned short h = f2bf(v);
    unsigned short l = f2bf(v - bf2f(h));
    *ph = h; *pl = l;
}

// ---------------- MFMA screen: 256 blocks x 64 rows; all 8192 codes.
// 512 threads = 8 waves; wave w owns cols nb*128 + w*16 + le. B double-buffered.
__global__ __launch_bounds__(512) void vq_screen_kernel(const ushort_t* __restrict__ xh,
                                                        const ushort_t* __restrict__ xl,
                                                        const ushort_t* __restrict__ ch,
                                                        const ushort_t* __restrict__ cl,
                                                        const float* __restrict__ sc,
                                                        float* __restrict__ out,
                                                        int* __restrict__ count,
                                                        int* __restrict__ list,
                                                        u64* __restrict__ qbest) {
    __shared__ float lm1[8][64];
    __shared__ int   li1[8][64];
    __shared__ float lm2[8][64];
    int tid = threadIdx.x;
    int row0 = blockIdx.x * 64;
    int w = tid >> 6, lane = tid & 63;
    int le = lane & 15, lk = lane >> 4;

    // A fragments in registers (reused across all codes)
    s16x8 a[4][4];
    #pragma unroll
    for (int i = 0; i < 4; ++i) {
        size_t ar = (size_t)(row0 + i * 16 + le) * 64 + lk * 8;
        a[i][0] = *(const s16x8*)(xh + ar);
        a[i][1] = *(const s16x8*)(xh + ar + 32);
        a[i][2] = *(const s16x8*)(xl + ar);
        a[i][3] = *(const s16x8*)(xl + ar + 32);
    }

    float m1[16], m2[16];
    int i1[16];
    #pragma unroll
    for (int s = 0; s < 16; ++s) { m1[s] = FLT_MAX; m2[s] = FLT_MAX; i1[s] = 0x7fffffff; }

    int colbase = w * 16 + le;
    // prefetch nb=0
    s16x8 bh0, bh1, bl0, bl1;
    float scv;
    {
        size_t br = (size_t)colbase * 64 + lk * 8;
        bh0 = *(const s16x8*)(ch + br);
        bh1 = *(const s16x8*)(ch + br + 32);
        bl0 = *(const s16x8*)(cl + br);
        bl1 = *(const s16x8*)(cl + br + 32);
        scv = sc[colbase];
    }

    for (int nb = 0; nb < 64; ++nb) {
        // prefetch nb+1 (wraps on last iter; redundant load, unused)
        int ncol = ((nb + 1) & 63) * 128 + colbase;
        size_t nbr = (size_t)ncol * 64 + lk * 8;
        s16x8 nh0 = *(const s16x8*)(ch + nbr);
        s16x8 nh1 = *(const s16x8*)(ch + nbr + 32);
        s16x8 nl0 = *(const s16x8*)(cl + nbr);
        s16x8 nl1 = *(const s16x8*)(cl + nbr + 32);
        float nsc = sc[ncol];

        f32x4 acc[4];
        #pragma unroll
        for (int i = 0; i < 4; ++i) acc[i] = (f32x4){0.f, 0.f, 0.f, 0.f};
        #pragma unroll
        for (int i = 0; i < 4; ++i) acc[i] = __builtin_amdgcn_mfma_f32_16x16x32_bf16(a[i][0], bh0, acc[i], 0, 0, 0);
        #pragma unroll
        for (int i = 0; i < 4; ++i) acc[i] = __builtin_amdgcn_mfma_f32_16x16x32_bf16(a[i][1], bh1, acc[i], 0, 0, 0);
        #pragma unroll
        for (int i = 0; i < 4; ++i) acc[i] = __builtin_amdgcn_mfma_f32_16x16x32_bf16(a[i][0], bl0, acc[i], 0, 0, 0);
        #pragma unroll
        for (int i = 0; i < 4; ++i) acc[i] = __builtin_amdgcn_mfma_f32_16x16x32_bf16(a[i][1], bl1, acc[i], 0, 0, 0);
        #pragma unroll
        for (int i = 0; i < 4; ++i) acc[i] = __builtin_amdgcn_mfma_f32_16x16x32_bf16(a[i][2], bh0, acc[i], 0, 0, 0);
        #pragma unroll
        for (int i = 0; i < 4; ++i) acc[i] = __builtin_amdgcn_mfma_f32_16x16x32_bf16(a[i][3], bh1, acc[i], 0, 0, 0);

        int col = nb * 128 + colbase;
        #pragma unroll
        for (int i = 0; i < 4; ++i) {
            #pragma unroll
            for (int reg = 0; reg < 4; ++reg) {
                int s = i * 4 + reg;
                float g = __fmaf_rn(-2.0f, acc[i][reg], scv);   // proxy (sx dropped)
                float om1 = m1[s];
                m2[s] = __builtin_amdgcn_fmed3f(om1, m2[s], g);
                i1[s] = (g < om1) ? col : i1[s];
                m1[s] = fminf(om1, g);
            }
        }
        bh0 = nh0; bh1 = nh1; bl0 = nl0; bl1 = nl1; scv = nsc;
    }

    // merge across the 16 le-lanes
    #pragma unroll
    for (int i = 0; i < 4; ++i) {
        #pragma unroll
        for (int reg = 0; reg < 4; ++reg) {
            int s = i * 4 + reg;
            float v1 = m1[s], v2 = m2[s];
            int ix = i1[s];
            #pragma unroll
            for (int mask = 1; mask < 16; mask <<= 1) {
                float o1 = __shfl_xor(v1, mask);
                int oi = __shfl_xor(ix, mask);
                float o2 = __shfl_xor(v2, mask);
                float n2 = fminf(fminf(v2, o2), fmaxf(v1, o1));
                ix = (o1 < v1) ? oi : ((o1 == v1 && oi < ix) ? oi : ix);
                v1 = fminf(v1, o1);
                v2 = n2;
            }
            if (le == 0) {
                int rl = i * 16 + lk * 4 + reg;
                lm1[w][rl] = v1; li1[w][rl] = ix; lm2[w][rl] = v2;
            }
        }
    }
    __syncthreads();
    if (tid < 64) {
        float M1 = FLT_MAX, M2 = FLT_MAX;
        int I1 = 0x7fffffff;
        #pragma unroll
        for (int ww = 0; ww < 8; ++ww) {
            float a1 = lm1[ww][tid], a2 = lm2[ww][tid];
            int ai = li1[ww][tid];
            M2 = fminf(fminf(M2, a2), fmaxf(M1, a1));
            if (a1 < M1 || (a1 == M1 && ai < I1)) I1 = ai;
            M1 = fminf(M1, a1);
        }
        int row = row0 + tid;
        if (M2 - M1 >= TAU) {
            out[row] = (float)I1;                  // provably the replica argmin
        } else {
            qbest[row] = 0xFFFFFFFFFFFFFFFFull;
            int pos = atomicAdd(count, 1);
            list[pos] = row;
        }
    }
}

// ---------------- fix: coalesced exact replica recompute of flagged rows.
// grid (256 rowchunks, 64 codetiles); block = 64 rows x 128 codes.
#define FLDP 68
__global__ __launch_bounds__(256) void vq_fix_kernel(const float* __restrict__ flat,
                                                     const float* __restrict__ cb,
                                                     const float* __restrict__ sx,
                                                     const float* __restrict__ sc,
                                                     const int* __restrict__ count,
                                                     const int* __restrict__ list,
                                                     u64* __restrict__ qbest) {
    __shared__ float xs[64 * FLDP];
    __shared__ float cs[128 * FLDP];
    __shared__ float sxs[64], scs[128];
    __shared__ int rowids[64];
    int n = *count;
    int rb = blockIdx.x;
    if (rb * 64 >= n) return;
    int nrows = n - rb * 64; if (nrows > 64) nrows = 64;
    int cb0 = blockIdx.y * 128;
    int tid = threadIdx.x;

    // stage rows (gather) + sx + rowids
    #pragma unroll
    for (int s = 0; s < 4; ++s) {
        int idx = tid + 256 * s;                   // 1024 float4s
        int r = idx >> 4, c = idx & 15;
        int rr = rb * 64 + r; if (rr >= n) rr = n - 1;
        int row = list[rr];
        if (c == 0) { rowids[r] = row; sxs[r] = sx[row]; }
        *(float4*)&xs[r * FLDP + c * 4] = *(const float4*)(flat + (size_t)row * 64 + c * 4);
    }
    // stage codes (coalesced)
    #pragma unroll
    for (int s = 0; s < 8; ++s) {
        int idx = tid + 256 * s;                   // 2048 float4s
        int r = idx >> 4, c = idx & 15;
        *(float4*)&cs[r * FLDP + c * 4] = *(const float4*)(cb + (size_t)(cb0 + r) * 64 + c * 4);
    }
    if (tid < 128) scs[tid] = sc[cb0 + tid];
    __syncthreads();

    int tr = tid >> 4, tc = tid & 15;              // rows tr+16i (i<4), codes tc+16j (j<8)
    float acc[4][8];
    #pragma unroll
    for (int i = 0; i < 4; ++i)
        #pragma unroll
        for (int j = 0; j < 8; ++j) acc[i][j] = 0.0f;

    for (int d = 0; d < 64; d += 4) {              // strictly ascending d: replica chain
        float4 ax[4], bc[8];
        #pragma unroll
        for (int i = 0; i < 4; ++i) ax[i] = *(const float4*)&xs[(tr + 16 * i) * FLDP + d];
        #pragma unroll
        for (int j = 0; j < 8; ++j) bc[j] = *(const float4*)&cs[(tc + 16 * j) * FLDP + d];
        #pragma unroll
        for (int i = 0; i < 4; ++i)
            #pragma unroll
            for (int j = 0; j < 8; ++j) {
                acc[i][j] = __fmaf_rn(ax[i].x, bc[j].x, acc[i][j]);
                acc[i][j] = __fmaf_rn(ax[i].y, bc[j].y, acc[i][j]);
                acc[i][j] = __fmaf_rn(ax[i].z, bc[j].z, acc[i][j]);
                acc[i][j] = __fmaf_rn(ax[i].w, bc[j].w, acc[i][j]);
            }
    }

    float best[4];
    int bidx[4];
    #pragma unroll
    for (int i = 0; i < 4; ++i) { best[i] = FLT_MAX; bidx[i] = 0x7fffffff; }
    #pragma unroll
    for (int j = 0; j < 8; ++j) {                  // ascending k within lane
        int k = cb0 + tc + 16 * j;
        float scj = scs[tc + 16 * j];
        #pragma unroll
        for (int i = 0; i < 4; ++i) {
            float t1 = __fadd_rn(sxs[tr + 16 * i], scj);
            float q = __fmaf_rn(-2.0f, acc[i][j], t1);   // replica q
            if (q < best[i]) { best[i] = q; bidx[i] = k; }
        }
    }

    // per-row merge across tc (reuse cs)
    __syncthreads();
    float* rmin = cs;                              // [64][16]
    int* ridx = (int*)(cs + 1024);                 // [64][16]
    #pragma unroll
    for (int i = 0; i < 4; ++i) {
        rmin[(tr + 16 * i) * 16 + tc] = best[i];
        ridx[(tr + 16 * i) * 16 + tc] = bidx[i];
    }
    __syncthreads();
    if (tid < nrows) {
        float m = FLT_MAX; int mi = 0x7fffffff;
        for (int t2 = 0; t2 < 16; ++t2) {
            float v = rmin[tid * 16 + t2];
            int ix = ridx[tid * 16 + t2];
            if (v < m || (v == m && ix < mi)) { m = v; mi = ix; }
        }
        u64 key = ((u64)__float_as_uint(m) << 32) | (unsigned)mi;  // q>0 -> order ok
        atomicMin(&qbest[rowids[tid]], key);
    }
}

// ---------------- vq_out: write flagged rows from qbest
__global__ __launch_bounds__(256) void vq_out_kernel(const int* __restrict__ count,
                                                     const int* __restrict__ list,
                                                     const u64* __restrict__ qbest,
                                                     float* __restrict__ out) {
    int pos = blockIdx.x * 256 + threadIdx.x;      // 16384
    if (pos >= *count) return;
    int row = list[pos];
    out[row] = (float)(unsigned)(qbest[row] & 0xffffffffull);
}

extern "C" void kernel_launch(void* const* d_in, const int* in_sizes, int n_in,
                              void* d_out, int out_size, void* d_ws, size_t ws_size,
                              hipStream_t stream) {
    const float* x  = (const float*)d_in[0];
    const float* w1 = (const float*)d_in[1];
    const float* b1 = (const float*)d_in[2];
    const float* w2 = (const float*)d_in[3];
    const float* b2 = (const float*)d_in[4];
    const float* w3 = (const float*)d_in[5];
    const float* b3 = (const float*)d_in[6];
    const float* cb = (const float*)d_in[7];

    float* ws   = (float*)d_ws;
    float* out1 = ws;                               // [0, 8388608)
    ushort_t* xh = (ushort_t*)(ws + 0);             // aliases out1 (post-conv2)
    ushort_t* xl = (ushort_t*)(ws + 524288);
    ushort_t* ch = (ushort_t*)(ws + 1048576);
    ushort_t* cl = (ushort_t*)(ws + 1310720);
    float* out2 = ws + 8388608;
    float* flat = ws + 12582912;
    float* sx   = ws + 13631488;
    float* sc   = ws + 13647872;
    int*   count = (int*)(ws + 13656064);
    int*   list  = (int*)(ws + 13656320);
    u64*   qbest = (u64*)(ws + 13672704);           // 8B aligned
    float* out  = (float*)d_out;

    hipLaunchKernelGGL(conv1_kernel,  dim3(1024, 2), dim3(256), 0, stream, x, w1, b1, out1);
    hipLaunchKernelGGL(conv2_kernel,  dim3(256, 8), dim3(256), 0, stream, out1, w2, b2, out2);
    hipLaunchKernelGGL(conv3_kernel,  dim3(64, 16), dim3(256), 0, stream, out2, w3, b3, flat);
    hipLaunchKernelGGL(rownorm_kernel, dim3(96), dim3(256), 0, stream, flat, cb, sx, sc);
    hipLaunchKernelGGL(split_kernel,  dim3(6144), dim3(256), 0, stream, flat, cb, xh, xl, ch, cl, count, out);
    hipLaunchKernelGGL(vq_screen_kernel, dim3(256), dim3(512), 0, stream,
                       xh, xl, ch, cl, sc, out, count, list, qbest);
    hipLaunchKernelGGL(vq_fix_kernel, dim3(256, 64), dim3(256), 0, stream,
                       flat, cb, sx, sc, count, list, qbest);
    hipLaunchKernelGGL(vq_out_kernel, dim3(64), dim3(256), 0, stream, count, list, qbest, out);
}